// Round 15
// baseline (426.332 us; speedup 1.0000x reference)
//
#include <hip/hip_runtime.h>
#include <cstddef>
#include <cstdint>

#define NG   100
#define NPG  1000
#define NN   (NG * NPG)       // 100000 nodes
#define NE   (NN * 16)        // 1600000 edges
#define EPG  (NE / NG)        // 16000 edges per graph (edges are graph-local)
#define CSRG 40000            // CSR capacity/graph (padded: sum max(ceil4(c),20) <= 39000)
#define MINREC 20             // min padded records per node (5 chunks)
#define FIN  64
#define HID  128
#define RD   64
#define SLOPE 0.01f
#define EPSV  1e-5f
#define NSTRIP 250            // nodes per GEMM/phi block (4 strips per graph)
#define GSN   40              // nodes per gather block (25 strips per graph)

using short8 = __attribute__((ext_vector_type(8))) short;   // 8 bf16 = 4 VGPRs
using f32x4  = __attribute__((ext_vector_type(4))) float;
typedef unsigned short u16;

__device__ __forceinline__ float leaky(float x) { return x >= 0.f ? x : SLOPE * x; }

// fp32 -> bf16 (round-to-nearest-even), bit pattern
__device__ __forceinline__ u16 f2bf(float f) {
  union { float f; unsigned u; } v; v.f = f;
  return (u16)((v.u + 0x7fffu + ((v.u >> 16) & 1u)) >> 16);
}
__device__ __forceinline__ float bf2f(u16 u) {
  union { unsigned u; float f; } v; v.u = ((unsigned)u) << 16;
  return v.f;
}

// XCD-affinity swizzle: block->XCD heuristic is blockIdx%8; pin graph g to
// XCD g%8 so producer/consumer blocks of one graph share an L2.
__device__ __forceinline__ bool swz(int b, int per_g, int& g, int& part) {
  const int xcd = b & 7;
  const int slot = b >> 3;
  g = xcd + 8 * (slot / per_g);
  part = slot % per_g;
  return g < NG;
}

// ---------------------------------------------------------------------------
// One-shot bf16 transpose of the four GEMM weight matrices: Wt[n][k]=W[k][n].
// ---------------------------------------------------------------------------
__global__ __launch_bounds__(256) void wt_k(const float* __restrict__ W1,
                                            const float* __restrict__ W2,
                                            const float* __restrict__ R1,
                                            const float* __restrict__ R2,
                                            u16* __restrict__ Wt1,
                                            u16* __restrict__ Wt2,
                                            u16* __restrict__ Rt1,
                                            u16* __restrict__ Rt2) {
  const int idx = blockIdx.x * 256 + threadIdx.x;  // 57344 total
  if (idx < FIN * HID) {
    const int n = idx >> 6, k = idx & 63;          // Wt1 [128][64]
    Wt1[idx] = f2bf(W1[k * HID + n]);
  } else {
    const int j = idx - FIN * HID;
    const int m = j >> 14, r = j & 16383;
    const int n = r >> 7, k = r & 127;
    const float* s = (m == 0) ? W2 : (m == 1) ? R1 : R2;
    u16* d = (m == 0) ? Wt2 : (m == 1) ? Rt1 : Rt2;
    d[r] = f2bf(s[k * HID + n]);
  }
}

// ---------------------------------------------------------------------------
// Degree histograms (global atomics; HW coalesces per-wave).
// ---------------------------------------------------------------------------
__global__ __launch_bounds__(256) void hist_k(const int* __restrict__ src,
                                              const int* __restrict__ dst,
                                              int* __restrict__ cout_,
                                              int* __restrict__ cin_) {
  const int e = blockIdx.x * 256 + threadIdx.x;
  if (e < NE) {
    atomicAdd(&cout_[src[e]], 1);
    atomicAdd(&cin_[dst[e]], 1);
  }
}

// ---------------------------------------------------------------------------
// Per-graph scan of PADDED segment sizes (vr = max(ceil4(cnt), 20)) ->
// offs + cursor; zero-fills each node's pad slots so the gather can run a
// fixed 5-chunk loop over zero-weight records.
// ---------------------------------------------------------------------------
__global__ __launch_bounds__(256) void scan2_k(const int* __restrict__ cin_,
                                               int* __restrict__ offs,
                                               int* __restrict__ cursor,
                                               unsigned* __restrict__ csr) {
  __shared__ int wtot[4];
  int g, part;
  if (!swz(blockIdx.x, 1, g, part)) return;   // grid 8*13 = 104, 4 idle
  const int t = threadIdx.x;
  const int lane = t & 63, wave = t >> 6;
  const int nb = g * NPG;
  int v[4], vr[4];
  int loc = 0;
#pragma unroll
  for (int k = 0; k < 4; ++k) {
    const int idx = t * 4 + k;
    v[k] = (idx < NPG) ? cin_[nb + idx] : 0;
    const int c4 = (v[k] + 3) & ~3;
    vr[k] = (idx < NPG) ? ((c4 > MINREC) ? c4 : MINREC) : 0;
    loc += vr[k];
  }
  int incl = loc;
#pragma unroll
  for (int d = 1; d < 64; d <<= 1) {
    const int x = __shfl_up(incl, d);
    if (lane >= d) incl += x;
  }
  if (lane == 63) wtot[wave] = incl;
  __syncthreads();
  int wexc = 0;
  for (int i = 0; i < wave; ++i) wexc += wtot[i];
  int run = g * CSRG + wexc + (incl - loc);
#pragma unroll
  for (int k = 0; k < 4; ++k) {
    const int idx = t * 4 + k;
    if (idx < NPG) {
      offs[nb + idx] = run;
      cursor[nb + idx] = run;
      for (int z = v[k]; z < vr[k]; ++z) csr[run + z] = 0;  // zero pad records
      run += vr[k];
    }
  }
}

// ---------------------------------------------------------------------------
// CSR fill: one edge per thread, global cursor atomics (dense, XCD-local).
// Record = packed dword {src_local:16 | bf16(w):16}.
// ---------------------------------------------------------------------------
__global__ __launch_bounds__(256) void fill_k(const int* __restrict__ src,
                                              const int* __restrict__ dst,
                                              const float* __restrict__ ew,
                                              int* __restrict__ cursor,
                                              unsigned* __restrict__ csr) {
  int g, part;
  if (!swz(blockIdx.x, 63, g, part)) return;  // 63*256 = 16128 >= EPG
  const int e0 = part * 256 + threadIdx.x;
  if (e0 >= EPG) return;
  const int nb = g * NPG;
  const int e = g * EPG + e0;
  const int s = src[e];
  const int d = dst[e];
  const float w = ew[e];
  const int pos = atomicAdd(&cursor[d], 1);
  csr[pos] = ((unsigned)(s - nb) << 16) | (unsigned)f2bf(w);
}

// ---------------------------------------------------------------------------
// Layer-1 GEMM (MFMA bf16), XCD-swizzled, register X-prefetch, bf16 output.
// ---------------------------------------------------------------------------
__global__ __launch_bounds__(256) void gemm1_k(const float* __restrict__ X,
                                               const u16* __restrict__ Wt,
                                               const int* __restrict__ cout_,
                                               u16* __restrict__ Y) {
  __shared__ u16 Xl[64 * FIN];
  __shared__ u16 Wl[HID * FIN];
  const int tid = threadIdx.x;
  const int wave = tid >> 6, lane = tid & 63, l15 = lane & 15, quad = lane >> 4;
  int g, part;
  if (!swz(blockIdx.x, 4, g, part)) return;
  const int base = g * NPG + part * NSTRIP;
  const int kq = tid & 15;
  const int srow = tid >> 4;

  for (int i = tid; i < HID * (FIN / 8); i += 256) {
    const int n = i >> 3, c = i & 7;
    const short8 w = *(const short8*)(Wt + n * FIN + c * 8);
    *(short8*)&Wl[n * FIN + ((c ^ (n & 7)) << 3)] = w;
  }
  float4 xpre[4];
#pragma unroll
  for (int it = 0; it < 4; ++it) {
    const int rowi = srow + it * 16;
    xpre[it] = (rowi < NSTRIP) ? *(const float4*)(X + (size_t)(base + rowi) * FIN + kq * 4)
                               : make_float4(0.f, 0.f, 0.f, 0.f);
  }
  for (int pass = 0; pass < 4; ++pass) {
    __syncthreads();
#pragma unroll
    for (int it = 0; it < 4; ++it) {
      const int r = srow + it * 16;
      ushort4 u = make_ushort4(f2bf(xpre[it].x), f2bf(xpre[it].y),
                               f2bf(xpre[it].z), f2bf(xpre[it].w));
      const int c = kq >> 1, half = kq & 1;
      *(ushort4*)&Xl[r * FIN + (((c ^ (r & 7)) << 3) | (half << 2))] = u;
    }
    __syncthreads();
    if (pass < 3) {
#pragma unroll
      for (int it = 0; it < 4; ++it) {
        const int rowi = (pass + 1) * 64 + srow + it * 16;
        xpre[it] = (rowi < NSTRIP) ? *(const float4*)(X + (size_t)(base + rowi) * FIN + kq * 4)
                                   : make_float4(0.f, 0.f, 0.f, 0.f);
      }
    }
    short8 a[2];
    const int arow = wave * 16 + l15;
#pragma unroll
    for (int kt = 0; kt < 2; ++kt)
      a[kt] = *(const short8*)&Xl[arow * FIN + (((kt * 4 + quad) ^ (l15 & 7)) << 3)];
    float sc[4];
    int rows[4];
#pragma unroll
    for (int r = 0; r < 4; ++r) {
      rows[r] = pass * 64 + wave * 16 + quad * 4 + r;
      sc[r] = (rows[r] < NSTRIP) ? rsqrtf(fmaxf((float)cout_[base + rows[r]], 1.0f)) : 0.f;
    }
#pragma unroll
    for (int ct = 0; ct < 8; ++ct) {
      f32x4 acc = {0.f, 0.f, 0.f, 0.f};
      const int brow = ct * 16 + l15;
#pragma unroll
      for (int kt = 0; kt < 2; ++kt) {
        const short8 b = *(const short8*)&Wl[brow * FIN + (((kt * 4 + quad) ^ (l15 & 7)) << 3)];
        acc = __builtin_amdgcn_mfma_f32_16x16x32_bf16(a[kt], b, acc, 0, 0, 0);
      }
      const int n = ct * 16 + l15;
#pragma unroll
      for (int r = 0; r < 4; ++r)
        if (rows[r] < NSTRIP) Y[(size_t)(base + rows[r]) * HID + n] = f2bf(acc[r] * sc[r]);
    }
  }
}

// inline GraphNorm affine from raw stats
__device__ __forceinline__ void norm_affine(const float* sx, const float* sq,
                                            const float* alpha, const float* gamma,
                                            const float* beta, int g, int c8,
                                            float* Av, float* Bv) {
  const float inv = 1.0f / NPG;
#pragma unroll
  for (int j = 0; j < 8; ++j) {
    const int f = c8 * 8 + j;
    const float mean = sx[g * HID + f] * inv;
    const float ex2 = sq[g * HID + f] * inv;
    const float am = alpha[f] * mean;
    const float var = fmaxf(ex2 - 2.0f * am * mean + am * am, 0.0f);
    const float A = gamma[f] * rsqrtf(var + EPSV);
    Av[j] = A;
    Bv[j] = beta[f] - A * am;
  }
}

// ---------------------------------------------------------------------------
// Layer-2 GEMM (MFMA bf16), fused norm (inline stats), X prefetch.
// ---------------------------------------------------------------------------
__global__ __launch_bounds__(256) void gemm_norm_k(const u16* __restrict__ Xb,
                                                   const u16* __restrict__ Wt,
                                                   const float* __restrict__ sx,
                                                   const float* __restrict__ sq,
                                                   const float* __restrict__ alpha,
                                                   const float* __restrict__ gamma,
                                                   const float* __restrict__ beta,
                                                   const int* __restrict__ cout_,
                                                   u16* __restrict__ Y) {
  __shared__ u16 Xl[64 * HID];
  __shared__ u16 Wl[HID * HID];
  const int tid = threadIdx.x;
  const int wave = tid >> 6, lane = tid & 63, l15 = lane & 15, quad = lane >> 4;
  int g, part;
  if (!swz(blockIdx.x, 4, g, part)) return;
  const int base = g * NPG + part * NSTRIP;
  const int c8 = tid & 15;
  const int srow = tid >> 4;

  for (int i = tid; i < HID * (HID / 8); i += 256) {
    const int n = i >> 4, c = i & 15;
    const short8 w = *(const short8*)(Wt + n * HID + c * 8);
    *(short8*)&Wl[n * HID + ((c ^ (n & 15)) << 3)] = w;
  }
  float Av[8], Bv[8];
  norm_affine(sx, sq, alpha, gamma, beta, g, c8, Av, Bv);
  const short8 z8 = {0, 0, 0, 0, 0, 0, 0, 0};
  short8 xpre[4];
#pragma unroll
  for (int it = 0; it < 4; ++it) {
    const int rowi = srow + it * 16;
    xpre[it] = (rowi < NSTRIP) ? *(const short8*)(Xb + (size_t)(base + rowi) * HID + c8 * 8) : z8;
  }
  for (int pass = 0; pass < 4; ++pass) {
    __syncthreads();
#pragma unroll
    for (int it = 0; it < 4; ++it) {
      const int r = srow + it * 16;
      const int rowi = pass * 64 + r;
      short8 o = z8;
      if (rowi < NSTRIP) {
#pragma unroll
        for (int j = 0; j < 8; ++j)
          o[j] = (short)f2bf(leaky(fmaf(Av[j], bf2f((u16)xpre[it][j]), Bv[j])));
      }
      *(short8*)&Xl[r * HID + ((c8 ^ (r & 15)) << 3)] = o;
    }
    __syncthreads();
    if (pass < 3) {
#pragma unroll
      for (int it = 0; it < 4; ++it) {
        const int rowi = (pass + 1) * 64 + srow + it * 16;
        xpre[it] = (rowi < NSTRIP) ? *(const short8*)(Xb + (size_t)(base + rowi) * HID + c8 * 8) : z8;
      }
    }
    short8 a[4];
    const int arow = wave * 16 + l15;
#pragma unroll
    for (int kt = 0; kt < 4; ++kt)
      a[kt] = *(const short8*)&Xl[arow * HID + (((kt * 4 + quad) ^ l15) << 3)];
    float sc[4];
    int rows[4];
#pragma unroll
    for (int r = 0; r < 4; ++r) {
      rows[r] = pass * 64 + wave * 16 + quad * 4 + r;
      sc[r] = (rows[r] < NSTRIP) ? rsqrtf(fmaxf((float)cout_[base + rows[r]], 1.0f)) : 0.f;
    }
#pragma unroll
    for (int ct = 0; ct < 8; ++ct) {
      f32x4 acc = {0.f, 0.f, 0.f, 0.f};
      const int brow = ct * 16 + l15;
#pragma unroll
      for (int kt = 0; kt < 4; ++kt) {
        const short8 b = *(const short8*)&Wl[brow * HID + (((kt * 4 + quad) ^ l15) << 3)];
        acc = __builtin_amdgcn_mfma_f32_16x16x32_bf16(a[kt], b, acc, 0, 0, 0);
      }
      const int n = ct * 16 + l15;
#pragma unroll
      for (int r = 0; r < 4; ++r)
        if (rows[r] < NSTRIP) Y[(size_t)(base + rows[r]) * HID + n] = f2bf(acc[r] * sc[r]);
    }
  }
}

// ---------------------------------------------------------------------------
// Readout phi+pool (MFMA bf16): 48 KB LDS, inline stats, X prefetch.
// ---------------------------------------------------------------------------
struct RedT { float red[16][HID]; float hred[16][HID]; };  // 16 KB
union ShT { u16 Xl[64 * HID]; RedT r; };                   // 16 KB

__global__ __launch_bounds__(256) void phi_pool_k(const u16* __restrict__ Xb,
                                                  const float* __restrict__ sx,
                                                  const float* __restrict__ sq,
                                                  const float* __restrict__ alpha,
                                                  const float* __restrict__ gamma,
                                                  const float* __restrict__ beta,
                                                  const u16* __restrict__ Wt,
                                                  const float* __restrict__ b1,
                                                  float* __restrict__ phi_sum,
                                                  float* __restrict__ h_sum) {
  __shared__ ShT sh;                    // 16 KB (Xl, then red/hred)
  __shared__ u16 Wl[HID * HID];         // 32 KB  -> 48 KB total
  const int tid = threadIdx.x;
  const int wave = tid >> 6, lane = tid & 63, l15 = lane & 15, quad = lane >> 4;
  int g, part;
  if (!swz(blockIdx.x, 4, g, part)) return;
  const int base = g * NPG + part * NSTRIP;
  const int c8 = tid & 15;
  const int srow = tid >> 4;

  for (int i = tid; i < HID * (HID / 8); i += 256) {
    const int n = i >> 4, c = i & 15;
    const short8 w = *(const short8*)(Wt + n * HID + c * 8);
    *(short8*)&Wl[n * HID + ((c ^ (n & 15)) << 3)] = w;
  }
  float Av[8], Bv[8];
  norm_affine(sx, sq, alpha, gamma, beta, g, c8, Av, Bv);
  float bcol[8];
#pragma unroll
  for (int ct = 0; ct < 8; ++ct) bcol[ct] = b1[ct * 16 + l15];

  float pooled[8] = {0.f, 0.f, 0.f, 0.f, 0.f, 0.f, 0.f, 0.f};
  float hp[8] = {0.f, 0.f, 0.f, 0.f, 0.f, 0.f, 0.f, 0.f};
  const short8 z8 = {0, 0, 0, 0, 0, 0, 0, 0};
  short8 xpre[4];
#pragma unroll
  for (int it = 0; it < 4; ++it) {
    const int rowi = srow + it * 16;
    xpre[it] = (rowi < NSTRIP) ? *(const short8*)(Xb + (size_t)(base + rowi) * HID + c8 * 8) : z8;
  }
  for (int pass = 0; pass < 4; ++pass) {
    __syncthreads();
#pragma unroll
    for (int it = 0; it < 4; ++it) {
      const int r = srow + it * 16;
      const int rowi = pass * 64 + r;
      short8 o = z8;
      if (rowi < NSTRIP) {
#pragma unroll
        for (int j = 0; j < 8; ++j) {
          const float xn = leaky(fmaf(Av[j], bf2f((u16)xpre[it][j]), Bv[j]));
          hp[j] += xn;
          o[j] = (short)f2bf(xn);
        }
      }
      *(short8*)&sh.Xl[r * HID + ((c8 ^ (r & 15)) << 3)] = o;
    }
    __syncthreads();
    if (pass < 3) {
#pragma unroll
      for (int it = 0; it < 4; ++it) {
        const int rowi = (pass + 1) * 64 + srow + it * 16;
        xpre[it] = (rowi < NSTRIP) ? *(const short8*)(Xb + (size_t)(base + rowi) * HID + c8 * 8) : z8;
      }
    }
    short8 a[4];
    const int arow = wave * 16 + l15;
#pragma unroll
    for (int kt = 0; kt < 4; ++kt)
      a[kt] = *(const short8*)&sh.Xl[arow * HID + (((kt * 4 + quad) ^ l15) << 3)];
#pragma unroll
    for (int ct = 0; ct < 8; ++ct) {
      f32x4 acc = {0.f, 0.f, 0.f, 0.f};
      const int brow = ct * 16 + l15;
#pragma unroll
      for (int kt = 0; kt < 4; ++kt) {
        const short8 b = *(const short8*)&Wl[brow * HID + (((kt * 4 + quad) ^ l15) << 3)];
        acc = __builtin_amdgcn_mfma_f32_16x16x32_bf16(a[kt], b, acc, 0, 0, 0);
      }
#pragma unroll
      for (int r = 0; r < 4; ++r) {
        const int rowi = pass * 64 + wave * 16 + quad * 4 + r;
        if (rowi < NSTRIP) pooled[ct] += leaky(acc[r] + bcol[ct]);
      }
    }
  }
  __syncthreads();   // all Xl reads done -> safe to overwrite with red/hred
  const int qi = wave * 4 + quad;
#pragma unroll
  for (int ct = 0; ct < 8; ++ct) sh.r.red[qi][ct * 16 + l15] = pooled[ct];
#pragma unroll
  for (int j = 0; j < 8; ++j) sh.r.hred[tid >> 4][(tid & 15) * 8 + j] = hp[j];
  __syncthreads();
  if (tid < HID) {
    float s = 0.f;
#pragma unroll
    for (int q = 0; q < 16; ++q) s += sh.r.red[q][tid];
    unsafeAtomicAdd(&phi_sum[g * HID + tid], s);
  } else {
    const int t = tid - HID;
    float s = 0.f;
#pragma unroll
    for (int rr = 0; rr < 16; ++rr) s += sh.r.hred[rr][t];
    unsafeAtomicAdd(&h_sum[g * HID + t], s);
  }
}

// ---------------------------------------------------------------------------
// Gather: scalar-pipe CSR, 4 chains/wave over PADDED segments: fixed 5-chunk
// interleave (no min/no tails; pad records are zero-weight), rare drains for
// cnt>20. 16 outstanding vmem per wave in the common loop.
// ---------------------------------------------------------------------------
__global__ __launch_bounds__(256) void gather_k(const u16* __restrict__ H,
                                                const unsigned* __restrict__ csr,
                                                const int* __restrict__ offs,
                                                const int* __restrict__ cin_,
                                                u16* __restrict__ AGG,
                                                float* __restrict__ sx,
                                                float* __restrict__ sq) {
  __shared__ float redx[4][HID];
  __shared__ float redq[4][HID];
  const int wave = threadIdx.x >> 6;
  const int lane = threadIdx.x & 63;
  int g, part;
  if (!swz(blockIdx.x, 25, g, part)) return;
  const int nb = g * NPG;
  const int base = nb + part * GSN;
  const int loff = lane * 2;
  const u16* __restrict__ Hg = H + (size_t)nb * HID;

  float sxa = 0.f, sxb = 0.f, sqa = 0.f, sqb = 0.f;
  for (int it = 0; it < 3; ++it) {            // node groups: 4, 4, 2
    const int nc = (it < 2) ? 4 : 2;
    int nn[4], off[4], cnt[4], c4p[4];
    float isq[4];
    const uint4* p[4];
#pragma unroll
    for (int c = 0; c < 4; ++c) {
      const int j = it * 4 + c;
      const int node = base + wave + ((j < 10) ? j : 0) * 4;
      nn[c] = node;
      const int nu = __builtin_amdgcn_readfirstlane(node);
      off[c] = __builtin_amdgcn_readfirstlane(offs[nu]);
      cnt[c] = (c < nc) ? __builtin_amdgcn_readfirstlane(cin_[nu]) : 0;
      const int cr = (cnt[c] + 3) & ~3;
      c4p[c] = ((cr > MINREC) ? cr : MINREC) >> 2;  // padded chunk count >= 5
      isq[c] = rsqrtf(fmaxf((float)cnt[c], 1.0f));
      p[c] = (const uint4*)__builtin_assume_aligned(csr + off[c], 16);
    }
    float ax[4] = {0.f, 0.f, 0.f, 0.f};
    float ay[4] = {0.f, 0.f, 0.f, 0.f};
#pragma unroll
    for (int t = 0; t < 5; ++t) {             // fixed: all chains have >=5 chunks
      uint4 r[4];
      unsigned u[4][4];
#pragma unroll
      for (int c = 0; c < 4; ++c)
        if (c < nc) {
          r[c] = p[c][t];
          u[c][0] = *(const unsigned*)(Hg + (size_t)(r[c].x >> 16) * HID + loff);
          u[c][1] = *(const unsigned*)(Hg + (size_t)(r[c].y >> 16) * HID + loff);
          u[c][2] = *(const unsigned*)(Hg + (size_t)(r[c].z >> 16) * HID + loff);
          u[c][3] = *(const unsigned*)(Hg + (size_t)(r[c].w >> 16) * HID + loff);
        }
#pragma unroll
      for (int c = 0; c < 4; ++c)
        if (c < nc) {
          const float w0 = bf2f((u16)(r[c].x & 0xffffu));
          const float w1 = bf2f((u16)(r[c].y & 0xffffu));
          const float w2 = bf2f((u16)(r[c].z & 0xffffu));
          const float w3 = bf2f((u16)(r[c].w & 0xffffu));
          ax[c] = fmaf(w0, __uint_as_float(u[c][0] << 16), ax[c]);
          ay[c] = fmaf(w0, __uint_as_float(u[c][0] & 0xffff0000u), ay[c]);
          ax[c] = fmaf(w1, __uint_as_float(u[c][1] << 16), ax[c]);
          ay[c] = fmaf(w1, __uint_as_float(u[c][1] & 0xffff0000u), ay[c]);
          ax[c] = fmaf(w2, __uint_as_float(u[c][2] << 16), ax[c]);
          ay[c] = fmaf(w2, __uint_as_float(u[c][2] & 0xffff0000u), ay[c]);
          ax[c] = fmaf(w3, __uint_as_float(u[c][3] << 16), ax[c]);
          ay[c] = fmaf(w3, __uint_as_float(u[c][3] & 0xffff0000u), ay[c]);
        }
    }
#pragma unroll
    for (int c = 0; c < 4; ++c) {             // rare drains (cnt > 20)
      for (int t = 5; t < c4p[c]; ++t) {
        const uint4 r = p[c][t];
        const unsigned u0 = *(const unsigned*)(Hg + (size_t)(r.x >> 16) * HID + loff);
        const unsigned u1 = *(const unsigned*)(Hg + (size_t)(r.y >> 16) * HID + loff);
        const unsigned u2 = *(const unsigned*)(Hg + (size_t)(r.z >> 16) * HID + loff);
        const unsigned u3 = *(const unsigned*)(Hg + (size_t)(r.w >> 16) * HID + loff);
        const float w0 = bf2f((u16)(r.x & 0xffffu));
        const float w1 = bf2f((u16)(r.y & 0xffffu));
        const float w2 = bf2f((u16)(r.z & 0xffffu));
        const float w3 = bf2f((u16)(r.w & 0xffffu));
        ax[c] = fmaf(w0, __uint_as_float(u0 << 16), ax[c]);
        ay[c] = fmaf(w0, __uint_as_float(u0 & 0xffff0000u), ay[c]);
        ax[c] = fmaf(w1, __uint_as_float(u1 << 16), ax[c]);
        ay[c] = fmaf(w1, __uint_as_float(u1 & 0xffff0000u), ay[c]);
        ax[c] = fmaf(w2, __uint_as_float(u2 << 16), ax[c]);
        ay[c] = fmaf(w2, __uint_as_float(u2 & 0xffff0000u), ay[c]);
        ax[c] = fmaf(w3, __uint_as_float(u3 << 16), ax[c]);
        ay[c] = fmaf(w3, __uint_as_float(u3 & 0xffff0000u), ay[c]);
      }
    }
#pragma unroll
    for (int c = 0; c < 4; ++c)
      if (c < nc) {
        const float rx = ax[c] * isq[c];
        const float ry = ay[c] * isq[c];
        *(unsigned*)(AGG + (size_t)nn[c] * HID + loff) =
            (unsigned)f2bf(rx) | ((unsigned)f2bf(ry) << 16);
        sxa += rx; sxb += ry;
        sqa += rx * rx; sqb += ry * ry;
      }
  }
  redx[wave][loff] = sxa; redx[wave][loff + 1] = sxb;
  redq[wave][loff] = sqa; redq[wave][loff + 1] = sqb;
  __syncthreads();
  const int tid = threadIdx.x;
  if (tid < HID) {
    unsafeAtomicAdd(&sx[g * HID + tid],
                    redx[0][tid] + redx[1][tid] + redx[2][tid] + redx[3][tid]);
  } else {
    const int t = tid - HID;
    unsafeAtomicAdd(&sq[g * HID + t],
                    redq[0][t] + redq[1][t] + redq[2][t] + redq[3][t]);
  }
}

// ---------------------------------------------------------------------------
// Readout part 2.
// ---------------------------------------------------------------------------
__global__ __launch_bounds__(64) void finalize_k(const float* __restrict__ phi_sum,
                                                 const float* __restrict__ h_sum,
                                                 const float* __restrict__ w2,
                                                 const float* __restrict__ b2,
                                                 float* __restrict__ out,
                                                 int roff, int moff) {
  const int g = blockIdx.x;
  const int j = threadIdx.x;  // 0..63
  float acc = b2[j];
#pragma unroll 8
  for (int k = 0; k < HID; ++k)
    acc += (phi_sum[g * HID + k] * (1.0f / NPG)) * w2[k * RD + j];
  const float r = leaky(acc);
  out[g * 384 + roff + j] = leaky(r);
  out[g * 384 + moff + j] = leaky(h_sum[g * HID + j] * (1.0f / NPG));
  out[g * 384 + moff + 64 + j] = leaky(h_sum[g * HID + 64 + j] * (1.0f / NPG));
}

// ---------------------------------------------------------------------------
extern "C" void kernel_launch(void* const* d_in, const int* in_sizes, int n_in,
                              void* d_out, int out_size, void* d_ws, size_t ws_size,
                              hipStream_t stream) {
  const float* node_feats = (const float*)d_in[0];
  const float* ew   = (const float*)d_in[1];
  const float* W1   = (const float*)d_in[2];
  const float* W2   = (const float*)d_in[3];
  const float* g1a  = (const float*)d_in[4];
  const float* g1g  = (const float*)d_in[5];
  const float* g1b  = (const float*)d_in[6];
  const float* g2a  = (const float*)d_in[7];
  const float* g2g  = (const float*)d_in[8];
  const float* g2b  = (const float*)d_in[9];
  const float* r1w1 = (const float*)d_in[10];
  const float* r1b1 = (const float*)d_in[11];
  const float* r1w2 = (const float*)d_in[12];
  const float* r1b2 = (const float*)d_in[13];
  const float* r2w1 = (const float*)d_in[14];
  const float* r2b1 = (const float*)d_in[15];
  const float* r2w2 = (const float*)d_in[16];
  const float* r2b2 = (const float*)d_in[17];
  const int* src = (const int*)d_in[18];
  const int* dst = (const int*)d_in[19];
  float* out = (float*)d_out;

  // workspace layout (zeroed region first: pooled sums + stats + cin/cout)
  char* wsb = (char*)d_ws;
  float* ps1     = (float*)wsb;                       // NG*HID x8, zeroed
  float* hs1     = ps1 + NG * HID;
  float* ps2     = hs1 + NG * HID;
  float* hs2     = ps2 + NG * HID;
  float* sx1     = hs2 + NG * HID;
  float* sq1     = sx1 + NG * HID;
  float* sx2     = sq1 + NG * HID;
  float* sq2     = sx2 + NG * HID;
  int*   cin     = (int*)(sq2 + NG * HID);            // NN } zeroed (hist)
  int*   cout_   = cin + NN;                          // NN }
  int*   offs    = cout_ + NN;                        // NN (scan2 store)
  int*   cursor  = offs + NN;                         // NN (scan2 store)
  unsigned* csr  = (unsigned*)(cursor + NN);          // NG*CSRG dwords (16 MB)
  u16*   Wt1     = (u16*)(csr + (size_t)NG * CSRG);   // 128*64
  u16*   Wt2     = Wt1 + HID * FIN;                   // 128*128 x3
  u16*   Rt1     = Wt2 + HID * HID;
  u16*   Rt2     = Rt1 + HID * HID;
  u16*   bufA    = Rt2 + HID * HID;                   // NN*HID bf16
  u16*   bufB    = bufA + (size_t)NN * HID;           // NN*HID bf16

  const size_t zero_bytes = (size_t)(8 * NG * HID) * sizeof(float) +
                            (size_t)(2 * NN) * sizeof(int);
  hipMemsetAsync(d_ws, 0, zero_bytes, stream);

  // weight transpose + CSR build pipeline (hist -> scan -> fill), per call
  wt_k<<<(FIN * HID + 3 * HID * HID) / 256, 256, 0, stream>>>(
      W1, W2, r1w1, r2w1, Wt1, Wt2, Rt1, Rt2);
  hist_k<<<(NE + 255) / 256, 256, 0, stream>>>(src, dst, cout_, cin);
  scan2_k<<<8 * 13, 256, 0, stream>>>(cin, offs, cursor, csr);
  fill_k<<<8 * 63 * 13, 256, 0, stream>>>(src, dst, ew, cursor, csr);

  const int gemm_grid = 8 * 4 * 13;     // XCD-swizzled, 4 strips/graph
  const int gather_grid = 8 * 25 * 13;  // XCD-swizzled, 25 strips/graph

  // ---- layer 1 ----
  gemm1_k<<<gemm_grid, 256, 0, stream>>>(node_feats, Wt1, cout_, bufA);
  gather_k<<<gather_grid, 256, 0, stream>>>(bufA, csr, offs, cin, bufB, sx1, sq1);
  phi_pool_k<<<gemm_grid, 256, 0, stream>>>(bufB, sx1, sq1, g1a, g1g, g1b,
                                            Rt1, r1b1, ps1, hs1);
  finalize_k<<<NG, 64, 0, stream>>>(ps1, hs1, r1w2, r1b2, out, 0, 64);

  // ---- layer 2 ----
  gemm_norm_k<<<gemm_grid, 256, 0, stream>>>(bufB, Wt2, sx1, sq1, g1a, g1g, g1b,
                                             cout_, bufA);
  gather_k<<<gather_grid, 256, 0, stream>>>(bufA, csr, offs, cin, bufB, sx2, sq2);
  phi_pool_k<<<gemm_grid, 256, 0, stream>>>(bufB, sx2, sq2, g2a, g2g, g2b,
                                            Rt2, r2b1, ps2, hs2);
  finalize_k<<<NG, 64, 0, stream>>>(ps2, hs2, r2w2, r2b2, out, 192, 256);
}

// Round 16
// 292.473 us; speedup vs baseline: 1.4577x; 1.4577x over previous
//
#include <hip/hip_runtime.h>
#include <cstddef>
#include <cstdint>

#define NG   100
#define NPG  1000
#define NN   (NG * NPG)       // 100000 nodes
#define NE   (NN * 16)        // 1600000 edges
#define EPG  (NE / NG)        // 16000 edges per graph (edges are graph-local)
#define CSRG 40000            // CSR capacity/graph (padded: sum max(ceil4(c),20))
#define MINREC 20             // min padded records per node (5 chunks)
#define FIN  64
#define HID  128
#define RD   64
#define SLOPE 0.01f
#define EPSV  1e-5f
#define NSTRIP 250            // nodes per GEMM/phi block (4 strips per graph)
#define GSN   40              // nodes per gather block (25 strips per graph)

using short8 = __attribute__((ext_vector_type(8))) short;   // 8 bf16 = 4 VGPRs
using f32x4  = __attribute__((ext_vector_type(4))) float;
typedef unsigned short u16;

__device__ __forceinline__ float leaky(float x) { return x >= 0.f ? x : SLOPE * x; }

// fp32 -> bf16 (round-to-nearest-even), bit pattern
__device__ __forceinline__ u16 f2bf(float f) {
  union { float f; unsigned u; } v; v.f = f;
  return (u16)((v.u + 0x7fffu + ((v.u >> 16) & 1u)) >> 16);
}
__device__ __forceinline__ float bf2f(u16 u) {
  union { unsigned u; float f; } v; v.u = ((unsigned)u) << 16;
  return v.f;
}

// XCD-affinity swizzle: block->XCD heuristic is blockIdx%8; pin graph g to
// XCD g%8 so producer/consumer blocks of one graph share an L2.
__device__ __forceinline__ bool swz(int b, int per_g, int& g, int& part) {
  const int xcd = b & 7;
  const int slot = b >> 3;
  g = xcd + 8 * (slot / per_g);
  part = slot % per_g;
  return g < NG;
}

// ---------------------------------------------------------------------------
// One-shot bf16 transpose of the four GEMM weight matrices: Wt[n][k]=W[k][n].
// ---------------------------------------------------------------------------
__global__ __launch_bounds__(256) void wt_k(const float* __restrict__ W1,
                                            const float* __restrict__ W2,
                                            const float* __restrict__ R1,
                                            const float* __restrict__ R2,
                                            u16* __restrict__ Wt1,
                                            u16* __restrict__ Wt2,
                                            u16* __restrict__ Rt1,
                                            u16* __restrict__ Rt2) {
  const int idx = blockIdx.x * 256 + threadIdx.x;  // 57344 total
  if (idx < FIN * HID) {
    const int n = idx >> 6, k = idx & 63;          // Wt1 [128][64]
    Wt1[idx] = f2bf(W1[k * HID + n]);
  } else {
    const int j = idx - FIN * HID;
    const int m = j >> 14, r = j & 16383;
    const int n = r >> 7, k = r & 127;
    const float* s = (m == 0) ? W2 : (m == 1) ? R1 : R2;
    u16* d = (m == 0) ? Wt2 : (m == 1) ? Rt1 : Rt2;
    d[r] = f2bf(s[k * HID + n]);
  }
}

// ---------------------------------------------------------------------------
// Per-graph CSR build: LDS histograms + shuffle scan + LDS cursors (the
// proven-fast form — global per-dst atomics are 2-4x worse, R7/R15), with
// MINREC-padded segments: vr = max(ceil4(cnt), 20), pad slots zero-filled
// so the gather runs a fixed 5-chunk interleave.
// ---------------------------------------------------------------------------
__global__ __launch_bounds__(1024) void build_k(const int* __restrict__ src,
                                                const int* __restrict__ dst,
                                                const float* __restrict__ ew,
                                                int* __restrict__ cin_,
                                                int* __restrict__ cout_,
                                                int* __restrict__ offs,
                                                unsigned* __restrict__ csr) {
  __shared__ int hin[NPG];
  __shared__ int hout[NPG];
  __shared__ int cur[NPG];
  __shared__ int wtot[16];
  int g, part;
  if (!swz(blockIdx.x, 1, g, part)) return;   // grid 8*13 = 104, 4 idle
  const int t = threadIdx.x;
  const int lane = t & 63, wave = t >> 6;
  const int nb = g * NPG, eb = g * EPG;
  if (t < NPG) { hin[t] = 0; hout[t] = 0; }
  __syncthreads();
  for (int e = t; e < EPG; e += 4096) {
    int s4[4], d4[4];
#pragma unroll
    for (int k = 0; k < 4; ++k) {
      const int ee = e + k * 1024;
      if (ee < EPG) { s4[k] = src[eb + ee]; d4[k] = dst[eb + ee]; }
      else d4[k] = -1;
    }
#pragma unroll
    for (int k = 0; k < 4; ++k)
      if (d4[k] >= 0) {
        atomicAdd(&hout[s4[k] - nb], 1);
        atomicAdd(&hin[d4[k] - nb], 1);
      }
  }
  __syncthreads();
  int v[4], vr[4];
  int loc = 0;
#pragma unroll
  for (int k = 0; k < 4; ++k) {
    const int idx = t * 4 + k;
    v[k] = (idx < NPG) ? hin[idx] : 0;
    const int c4 = (v[k] + 3) & ~3;
    vr[k] = (idx < NPG) ? ((c4 > MINREC) ? c4 : MINREC) : 0;
    loc += vr[k];
  }
  int incl = loc;
#pragma unroll
  for (int d = 1; d < 64; d <<= 1) {
    const int x = __shfl_up(incl, d);
    if (lane >= d) incl += x;
  }
  if (lane == 63) wtot[wave] = incl;
  if (t < NPG) { cin_[nb + t] = hin[t]; cout_[nb + t] = hout[t]; }
  __syncthreads();
  int wexc = 0;
  for (int i = 0; i < wave; ++i) wexc += wtot[i];
  int run = g * CSRG + wexc + (incl - loc);
#pragma unroll
  for (int k = 0; k < 4; ++k) {
    const int idx = t * 4 + k;
    if (idx < NPG) {
      offs[nb + idx] = run;
      cur[idx] = run;
      for (int z = v[k]; z < vr[k]; ++z) csr[run + z] = 0;  // zero pad records
      run += vr[k];
    }
  }
  __syncthreads();
  for (int e = t; e < EPG; e += 4096) {
    int s4[4], d4[4]; float w4[4];
#pragma unroll
    for (int k = 0; k < 4; ++k) {
      const int ee = e + k * 1024;
      if (ee < EPG) { s4[k] = src[eb + ee]; d4[k] = dst[eb + ee]; w4[k] = ew[eb + ee]; }
      else d4[k] = -1;
    }
#pragma unroll
    for (int k = 0; k < 4; ++k)
      if (d4[k] >= 0) {
        const int pos = atomicAdd(&cur[d4[k] - nb], 1);
        csr[pos] = ((unsigned)(s4[k] - nb) << 16) | (unsigned)f2bf(w4[k]);
      }
  }
}

// ---------------------------------------------------------------------------
// Layer-1 GEMM (MFMA bf16), XCD-swizzled, register X-prefetch, bf16 output.
// ---------------------------------------------------------------------------
__global__ __launch_bounds__(256) void gemm1_k(const float* __restrict__ X,
                                               const u16* __restrict__ Wt,
                                               const int* __restrict__ cout_,
                                               u16* __restrict__ Y) {
  __shared__ u16 Xl[64 * FIN];
  __shared__ u16 Wl[HID * FIN];
  const int tid = threadIdx.x;
  const int wave = tid >> 6, lane = tid & 63, l15 = lane & 15, quad = lane >> 4;
  int g, part;
  if (!swz(blockIdx.x, 4, g, part)) return;
  const int base = g * NPG + part * NSTRIP;
  const int kq = tid & 15;
  const int srow = tid >> 4;

  for (int i = tid; i < HID * (FIN / 8); i += 256) {
    const int n = i >> 3, c = i & 7;
    const short8 w = *(const short8*)(Wt + n * FIN + c * 8);
    *(short8*)&Wl[n * FIN + ((c ^ (n & 7)) << 3)] = w;
  }
  float4 xpre[4];
#pragma unroll
  for (int it = 0; it < 4; ++it) {
    const int rowi = srow + it * 16;
    xpre[it] = (rowi < NSTRIP) ? *(const float4*)(X + (size_t)(base + rowi) * FIN + kq * 4)
                               : make_float4(0.f, 0.f, 0.f, 0.f);
  }
  for (int pass = 0; pass < 4; ++pass) {
    __syncthreads();
#pragma unroll
    for (int it = 0; it < 4; ++it) {
      const int r = srow + it * 16;
      ushort4 u = make_ushort4(f2bf(xpre[it].x), f2bf(xpre[it].y),
                               f2bf(xpre[it].z), f2bf(xpre[it].w));
      const int c = kq >> 1, half = kq & 1;
      *(ushort4*)&Xl[r * FIN + (((c ^ (r & 7)) << 3) | (half << 2))] = u;
    }
    __syncthreads();
    if (pass < 3) {
#pragma unroll
      for (int it = 0; it < 4; ++it) {
        const int rowi = (pass + 1) * 64 + srow + it * 16;
        xpre[it] = (rowi < NSTRIP) ? *(const float4*)(X + (size_t)(base + rowi) * FIN + kq * 4)
                                   : make_float4(0.f, 0.f, 0.f, 0.f);
      }
    }
    short8 a[2];
    const int arow = wave * 16 + l15;
#pragma unroll
    for (int kt = 0; kt < 2; ++kt)
      a[kt] = *(const short8*)&Xl[arow * FIN + (((kt * 4 + quad) ^ (l15 & 7)) << 3)];
    float sc[4];
    int rows[4];
#pragma unroll
    for (int r = 0; r < 4; ++r) {
      rows[r] = pass * 64 + wave * 16 + quad * 4 + r;
      sc[r] = (rows[r] < NSTRIP) ? rsqrtf(fmaxf((float)cout_[base + rows[r]], 1.0f)) : 0.f;
    }
#pragma unroll
    for (int ct = 0; ct < 8; ++ct) {
      f32x4 acc = {0.f, 0.f, 0.f, 0.f};
      const int brow = ct * 16 + l15;
#pragma unroll
      for (int kt = 0; kt < 2; ++kt) {
        const short8 b = *(const short8*)&Wl[brow * FIN + (((kt * 4 + quad) ^ (l15 & 7)) << 3)];
        acc = __builtin_amdgcn_mfma_f32_16x16x32_bf16(a[kt], b, acc, 0, 0, 0);
      }
      const int n = ct * 16 + l15;
#pragma unroll
      for (int r = 0; r < 4; ++r)
        if (rows[r] < NSTRIP) Y[(size_t)(base + rows[r]) * HID + n] = f2bf(acc[r] * sc[r]);
    }
  }
}

// inline GraphNorm affine from raw stats
__device__ __forceinline__ void norm_affine(const float* sx, const float* sq,
                                            const float* alpha, const float* gamma,
                                            const float* beta, int g, int c8,
                                            float* Av, float* Bv) {
  const float inv = 1.0f / NPG;
#pragma unroll
  for (int j = 0; j < 8; ++j) {
    const int f = c8 * 8 + j;
    const float mean = sx[g * HID + f] * inv;
    const float ex2 = sq[g * HID + f] * inv;
    const float am = alpha[f] * mean;
    const float var = fmaxf(ex2 - 2.0f * am * mean + am * am, 0.0f);
    const float A = gamma[f] * rsqrtf(var + EPSV);
    Av[j] = A;
    Bv[j] = beta[f] - A * am;
  }
}

// ---------------------------------------------------------------------------
// Layer-2 GEMM (MFMA bf16), fused norm (inline stats), X prefetch.
// ---------------------------------------------------------------------------
__global__ __launch_bounds__(256) void gemm_norm_k(const u16* __restrict__ Xb,
                                                   const u16* __restrict__ Wt,
                                                   const float* __restrict__ sx,
                                                   const float* __restrict__ sq,
                                                   const float* __restrict__ alpha,
                                                   const float* __restrict__ gamma,
                                                   const float* __restrict__ beta,
                                                   const int* __restrict__ cout_,
                                                   u16* __restrict__ Y) {
  __shared__ u16 Xl[64 * HID];
  __shared__ u16 Wl[HID * HID];
  const int tid = threadIdx.x;
  const int wave = tid >> 6, lane = tid & 63, l15 = lane & 15, quad = lane >> 4;
  int g, part;
  if (!swz(blockIdx.x, 4, g, part)) return;
  const int base = g * NPG + part * NSTRIP;
  const int c8 = tid & 15;
  const int srow = tid >> 4;

  for (int i = tid; i < HID * (HID / 8); i += 256) {
    const int n = i >> 4, c = i & 15;
    const short8 w = *(const short8*)(Wt + n * HID + c * 8);
    *(short8*)&Wl[n * HID + ((c ^ (n & 15)) << 3)] = w;
  }
  float Av[8], Bv[8];
  norm_affine(sx, sq, alpha, gamma, beta, g, c8, Av, Bv);
  const short8 z8 = {0, 0, 0, 0, 0, 0, 0, 0};
  short8 xpre[4];
#pragma unroll
  for (int it = 0; it < 4; ++it) {
    const int rowi = srow + it * 16;
    xpre[it] = (rowi < NSTRIP) ? *(const short8*)(Xb + (size_t)(base + rowi) * HID + c8 * 8) : z8;
  }
  for (int pass = 0; pass < 4; ++pass) {
    __syncthreads();
#pragma unroll
    for (int it = 0; it < 4; ++it) {
      const int r = srow + it * 16;
      const int rowi = pass * 64 + r;
      short8 o = z8;
      if (rowi < NSTRIP) {
#pragma unroll
        for (int j = 0; j < 8; ++j)
          o[j] = (short)f2bf(leaky(fmaf(Av[j], bf2f((u16)xpre[it][j]), Bv[j])));
      }
      *(short8*)&Xl[r * HID + ((c8 ^ (r & 15)) << 3)] = o;
    }
    __syncthreads();
    if (pass < 3) {
#pragma unroll
      for (int it = 0; it < 4; ++it) {
        const int rowi = (pass + 1) * 64 + srow + it * 16;
        xpre[it] = (rowi < NSTRIP) ? *(const short8*)(Xb + (size_t)(base + rowi) * HID + c8 * 8) : z8;
      }
    }
    short8 a[4];
    const int arow = wave * 16 + l15;
#pragma unroll
    for (int kt = 0; kt < 4; ++kt)
      a[kt] = *(const short8*)&Xl[arow * HID + (((kt * 4 + quad) ^ l15) << 3)];
    float sc[4];
    int rows[4];
#pragma unroll
    for (int r = 0; r < 4; ++r) {
      rows[r] = pass * 64 + wave * 16 + quad * 4 + r;
      sc[r] = (rows[r] < NSTRIP) ? rsqrtf(fmaxf((float)cout_[base + rows[r]], 1.0f)) : 0.f;
    }
#pragma unroll
    for (int ct = 0; ct < 8; ++ct) {
      f32x4 acc = {0.f, 0.f, 0.f, 0.f};
      const int brow = ct * 16 + l15;
#pragma unroll
      for (int kt = 0; kt < 4; ++kt) {
        const short8 b = *(const short8*)&Wl[brow * HID + (((kt * 4 + quad) ^ l15) << 3)];
        acc = __builtin_amdgcn_mfma_f32_16x16x32_bf16(a[kt], b, acc, 0, 0, 0);
      }
      const int n = ct * 16 + l15;
#pragma unroll
      for (int r = 0; r < 4; ++r)
        if (rows[r] < NSTRIP) Y[(size_t)(base + rows[r]) * HID + n] = f2bf(acc[r] * sc[r]);
    }
  }
}

// ---------------------------------------------------------------------------
// Readout phi+pool (MFMA bf16): 48 KB LDS, inline stats, X prefetch.
// ---------------------------------------------------------------------------
struct RedT { float red[16][HID]; float hred[16][HID]; };  // 16 KB
union ShT { u16 Xl[64 * HID]; RedT r; };                   // 16 KB

__global__ __launch_bounds__(256) void phi_pool_k(const u16* __restrict__ Xb,
                                                  const float* __restrict__ sx,
                                                  const float* __restrict__ sq,
                                                  const float* __restrict__ alpha,
                                                  const float* __restrict__ gamma,
                                                  const float* __restrict__ beta,
                                                  const u16* __restrict__ Wt,
                                                  const float* __restrict__ b1,
                                                  float* __restrict__ phi_sum,
                                                  float* __restrict__ h_sum) {
  __shared__ ShT sh;                    // 16 KB (Xl, then red/hred)
  __shared__ u16 Wl[HID * HID];         // 32 KB  -> 48 KB total
  const int tid = threadIdx.x;
  const int wave = tid >> 6, lane = tid & 63, l15 = lane & 15, quad = lane >> 4;
  int g, part;
  if (!swz(blockIdx.x, 4, g, part)) return;
  const int base = g * NPG + part * NSTRIP;
  const int c8 = tid & 15;
  const int srow = tid >> 4;

  for (int i = tid; i < HID * (HID / 8); i += 256) {
    const int n = i >> 4, c = i & 15;
    const short8 w = *(const short8*)(Wt + n * HID + c * 8);
    *(short8*)&Wl[n * HID + ((c ^ (n & 15)) << 3)] = w;
  }
  float Av[8], Bv[8];
  norm_affine(sx, sq, alpha, gamma, beta, g, c8, Av, Bv);
  float bcol[8];
#pragma unroll
  for (int ct = 0; ct < 8; ++ct) bcol[ct] = b1[ct * 16 + l15];

  float pooled[8] = {0.f, 0.f, 0.f, 0.f, 0.f, 0.f, 0.f, 0.f};
  float hp[8] = {0.f, 0.f, 0.f, 0.f, 0.f, 0.f, 0.f, 0.f};
  const short8 z8 = {0, 0, 0, 0, 0, 0, 0, 0};
  short8 xpre[4];
#pragma unroll
  for (int it = 0; it < 4; ++it) {
    const int rowi = srow + it * 16;
    xpre[it] = (rowi < NSTRIP) ? *(const short8*)(Xb + (size_t)(base + rowi) * HID + c8 * 8) : z8;
  }
  for (int pass = 0; pass < 4; ++pass) {
    __syncthreads();
#pragma unroll
    for (int it = 0; it < 4; ++it) {
      const int r = srow + it * 16;
      const int rowi = pass * 64 + r;
      short8 o = z8;
      if (rowi < NSTRIP) {
#pragma unroll
        for (int j = 0; j < 8; ++j) {
          const float xn = leaky(fmaf(Av[j], bf2f((u16)xpre[it][j]), Bv[j]));
          hp[j] += xn;
          o[j] = (short)f2bf(xn);
        }
      }
      *(short8*)&sh.Xl[r * HID + ((c8 ^ (r & 15)) << 3)] = o;
    }
    __syncthreads();
    if (pass < 3) {
#pragma unroll
      for (int it = 0; it < 4; ++it) {
        const int rowi = (pass + 1) * 64 + srow + it * 16;
        xpre[it] = (rowi < NSTRIP) ? *(const short8*)(Xb + (size_t)(base + rowi) * HID + c8 * 8) : z8;
      }
    }
    short8 a[4];
    const int arow = wave * 16 + l15;
#pragma unroll
    for (int kt = 0; kt < 4; ++kt)
      a[kt] = *(const short8*)&sh.Xl[arow * HID + (((kt * 4 + quad) ^ l15) << 3)];
#pragma unroll
    for (int ct = 0; ct < 8; ++ct) {
      f32x4 acc = {0.f, 0.f, 0.f, 0.f};
      const int brow = ct * 16 + l15;
#pragma unroll
      for (int kt = 0; kt < 4; ++kt) {
        const short8 b = *(const short8*)&Wl[brow * HID + (((kt * 4 + quad) ^ l15) << 3)];
        acc = __builtin_amdgcn_mfma_f32_16x16x32_bf16(a[kt], b, acc, 0, 0, 0);
      }
#pragma unroll
      for (int r = 0; r < 4; ++r) {
        const int rowi = pass * 64 + wave * 16 + quad * 4 + r;
        if (rowi < NSTRIP) pooled[ct] += leaky(acc[r] + bcol[ct]);
      }
    }
  }
  __syncthreads();   // all Xl reads done -> safe to overwrite with red/hred
  const int qi = wave * 4 + quad;
#pragma unroll
  for (int ct = 0; ct < 8; ++ct) sh.r.red[qi][ct * 16 + l15] = pooled[ct];
#pragma unroll
  for (int j = 0; j < 8; ++j) sh.r.hred[tid >> 4][(tid & 15) * 8 + j] = hp[j];
  __syncthreads();
  if (tid < HID) {
    float s = 0.f;
#pragma unroll
    for (int q = 0; q < 16; ++q) s += sh.r.red[q][tid];
    unsafeAtomicAdd(&phi_sum[g * HID + tid], s);
  } else {
    const int t = tid - HID;
    float s = 0.f;
#pragma unroll
    for (int rr = 0; rr < 16; ++rr) s += sh.r.hred[rr][t];
    unsafeAtomicAdd(&h_sum[g * HID + t], s);
  }
}

// ---------------------------------------------------------------------------
// Gather: scalar-pipe CSR, 4 chains/wave over PADDED segments: fixed 5-chunk
// interleave (pad records are zero-weight), rare drains for cnt>20.
// ---------------------------------------------------------------------------
__global__ __launch_bounds__(256) void gather_k(const u16* __restrict__ H,
                                                const unsigned* __restrict__ csr,
                                                const int* __restrict__ offs,
                                                const int* __restrict__ cin_,
                                                u16* __restrict__ AGG,
                                                float* __restrict__ sx,
                                                float* __restrict__ sq) {
  __shared__ float redx[4][HID];
  __shared__ float redq[4][HID];
  const int wave = threadIdx.x >> 6;
  const int lane = threadIdx.x & 63;
  int g, part;
  if (!swz(blockIdx.x, 25, g, part)) return;
  const int nb = g * NPG;
  const int base = nb + part * GSN;
  const int loff = lane * 2;
  const u16* __restrict__ Hg = H + (size_t)nb * HID;

  float sxa = 0.f, sxb = 0.f, sqa = 0.f, sqb = 0.f;
  for (int it = 0; it < 3; ++it) {            // node groups: 4, 4, 2
    const int nc = (it < 2) ? 4 : 2;
    int nn[4], off[4], cnt[4], c4p[4];
    float isq[4];
    const uint4* p[4];
#pragma unroll
    for (int c = 0; c < 4; ++c) {
      const int j = it * 4 + c;
      const int node = base + wave + ((j < 10) ? j : 0) * 4;
      nn[c] = node;
      const int nu = __builtin_amdgcn_readfirstlane(node);
      off[c] = __builtin_amdgcn_readfirstlane(offs[nu]);
      cnt[c] = (c < nc) ? __builtin_amdgcn_readfirstlane(cin_[nu]) : 0;
      const int cr = (cnt[c] + 3) & ~3;
      c4p[c] = ((cr > MINREC) ? cr : MINREC) >> 2;  // padded chunk count >= 5
      isq[c] = rsqrtf(fmaxf((float)cnt[c], 1.0f));
      p[c] = (const uint4*)__builtin_assume_aligned(csr + off[c], 16);
    }
    float ax[4] = {0.f, 0.f, 0.f, 0.f};
    float ay[4] = {0.f, 0.f, 0.f, 0.f};
#pragma unroll
    for (int t = 0; t < 5; ++t) {             // fixed: all chains have >=5 chunks
      uint4 r[4];
      unsigned u[4][4];
#pragma unroll
      for (int c = 0; c < 4; ++c)
        if (c < nc) {
          r[c] = p[c][t];
          u[c][0] = *(const unsigned*)(Hg + (size_t)(r[c].x >> 16) * HID + loff);
          u[c][1] = *(const unsigned*)(Hg + (size_t)(r[c].y >> 16) * HID + loff);
          u[c][2] = *(const unsigned*)(Hg + (size_t)(r[c].z >> 16) * HID + loff);
          u[c][3] = *(const unsigned*)(Hg + (size_t)(r[c].w >> 16) * HID + loff);
        }
#pragma unroll
      for (int c = 0; c < 4; ++c)
        if (c < nc) {
          const float w0 = bf2f((u16)(r[c].x & 0xffffu));
          const float w1 = bf2f((u16)(r[c].y & 0xffffu));
          const float w2 = bf2f((u16)(r[c].z & 0xffffu));
          const float w3 = bf2f((u16)(r[c].w & 0xffffu));
          ax[c] = fmaf(w0, __uint_as_float(u[c][0] << 16), ax[c]);
          ay[c] = fmaf(w0, __uint_as_float(u[c][0] & 0xffff0000u), ay[c]);
          ax[c] = fmaf(w1, __uint_as_float(u[c][1] << 16), ax[c]);
          ay[c] = fmaf(w1, __uint_as_float(u[c][1] & 0xffff0000u), ay[c]);
          ax[c] = fmaf(w2, __uint_as_float(u[c][2] << 16), ax[c]);
          ay[c] = fmaf(w2, __uint_as_float(u[c][2] & 0xffff0000u), ay[c]);
          ax[c] = fmaf(w3, __uint_as_float(u[c][3] << 16), ax[c]);
          ay[c] = fmaf(w3, __uint_as_float(u[c][3] & 0xffff0000u), ay[c]);
        }
    }
#pragma unroll
    for (int c = 0; c < 4; ++c) {             // rare drains (cnt > 20)
      for (int t = 5; t < c4p[c]; ++t) {
        const uint4 r = p[c][t];
        const unsigned u0 = *(const unsigned*)(Hg + (size_t)(r.x >> 16) * HID + loff);
        const unsigned u1 = *(const unsigned*)(Hg + (size_t)(r.y >> 16) * HID + loff);
        const unsigned u2 = *(const unsigned*)(Hg + (size_t)(r.z >> 16) * HID + loff);
        const unsigned u3 = *(const unsigned*)(Hg + (size_t)(r.w >> 16) * HID + loff);
        const float w0 = bf2f((u16)(r.x & 0xffffu));
        const float w1 = bf2f((u16)(r.y & 0xffffu));
        const float w2 = bf2f((u16)(r.z & 0xffffu));
        const float w3 = bf2f((u16)(r.w & 0xffffu));
        ax[c] = fmaf(w0, __uint_as_float(u0 << 16), ax[c]);
        ay[c] = fmaf(w0, __uint_as_float(u0 & 0xffff0000u), ay[c]);
        ax[c] = fmaf(w1, __uint_as_float(u1 << 16), ax[c]);
        ay[c] = fmaf(w1, __uint_as_float(u1 & 0xffff0000u), ay[c]);
        ax[c] = fmaf(w2, __uint_as_float(u2 << 16), ax[c]);
        ay[c] = fmaf(w2, __uint_as_float(u2 & 0xffff0000u), ay[c]);
        ax[c] = fmaf(w3, __uint_as_float(u3 << 16), ax[c]);
        ay[c] = fmaf(w3, __uint_as_float(u3 & 0xffff0000u), ay[c]);
      }
    }
#pragma unroll
    for (int c = 0; c < 4; ++c)
      if (c < nc) {
        const float rx = ax[c] * isq[c];
        const float ry = ay[c] * isq[c];
        *(unsigned*)(AGG + (size_t)nn[c] * HID + loff) =
            (unsigned)f2bf(rx) | ((unsigned)f2bf(ry) << 16);
        sxa += rx; sxb += ry;
        sqa += rx * rx; sqb += ry * ry;
      }
  }
  redx[wave][loff] = sxa; redx[wave][loff + 1] = sxb;
  redq[wave][loff] = sqa; redq[wave][loff + 1] = sqb;
  __syncthreads();
  const int tid = threadIdx.x;
  if (tid < HID) {
    unsafeAtomicAdd(&sx[g * HID + tid],
                    redx[0][tid] + redx[1][tid] + redx[2][tid] + redx[3][tid]);
  } else {
    const int t = tid - HID;
    unsafeAtomicAdd(&sq[g * HID + t],
                    redq[0][t] + redq[1][t] + redq[2][t] + redq[3][t]);
  }
}

// ---------------------------------------------------------------------------
// Readout part 2.
// ---------------------------------------------------------------------------
__global__ __launch_bounds__(64) void finalize_k(const float* __restrict__ phi_sum,
                                                 const float* __restrict__ h_sum,
                                                 const float* __restrict__ w2,
                                                 const float* __restrict__ b2,
                                                 float* __restrict__ out,
                                                 int roff, int moff) {
  const int g = blockIdx.x;
  const int j = threadIdx.x;  // 0..63
  float acc = b2[j];
#pragma unroll 8
  for (int k = 0; k < HID; ++k)
    acc += (phi_sum[g * HID + k] * (1.0f / NPG)) * w2[k * RD + j];
  const float r = leaky(acc);
  out[g * 384 + roff + j] = leaky(r);
  out[g * 384 + moff + j] = leaky(h_sum[g * HID + j] * (1.0f / NPG));
  out[g * 384 + moff + 64 + j] = leaky(h_sum[g * HID + 64 + j] * (1.0f / NPG));
}

// ---------------------------------------------------------------------------
extern "C" void kernel_launch(void* const* d_in, const int* in_sizes, int n_in,
                              void* d_out, int out_size, void* d_ws, size_t ws_size,
                              hipStream_t stream) {
  const float* node_feats = (const float*)d_in[0];
  const float* ew   = (const float*)d_in[1];
  const float* W1   = (const float*)d_in[2];
  const float* W2   = (const float*)d_in[3];
  const float* g1a  = (const float*)d_in[4];
  const float* g1g  = (const float*)d_in[5];
  const float* g1b  = (const float*)d_in[6];
  const float* g2a  = (const float*)d_in[7];
  const float* g2g  = (const float*)d_in[8];
  const float* g2b  = (const float*)d_in[9];
  const float* r1w1 = (const float*)d_in[10];
  const float* r1b1 = (const float*)d_in[11];
  const float* r1w2 = (const float*)d_in[12];
  const float* r1b2 = (const float*)d_in[13];
  const float* r2w1 = (const float*)d_in[14];
  const float* r2b1 = (const float*)d_in[15];
  const float* r2w2 = (const float*)d_in[16];
  const float* r2b2 = (const float*)d_in[17];
  const int* src = (const int*)d_in[18];
  const int* dst = (const int*)d_in[19];
  float* out = (float*)d_out;

  // workspace layout (zeroed region first: pooled sums + stats)
  char* wsb = (char*)d_ws;
  float* ps1     = (float*)wsb;                       // NG*HID x8, zeroed
  float* hs1     = ps1 + NG * HID;
  float* ps2     = hs1 + NG * HID;
  float* hs2     = ps2 + NG * HID;
  float* sx1     = hs2 + NG * HID;
  float* sq1     = sx1 + NG * HID;
  float* sx2     = sq1 + NG * HID;
  float* sq2     = sx2 + NG * HID;
  int*   cin     = (int*)(sq2 + NG * HID);            // NN (direct store)
  int*   cout_   = cin + NN;                          // NN (direct store)
  int*   offs    = cout_ + NN;                        // NN (direct store)
  unsigned* csr  = (unsigned*)(offs + NN);            // NG*CSRG dwords (16 MB)
  u16*   Wt1     = (u16*)(csr + (size_t)NG * CSRG);   // 128*64
  u16*   Wt2     = Wt1 + HID * FIN;                   // 128*128 x3
  u16*   Rt1     = Wt2 + HID * HID;
  u16*   Rt2     = Rt1 + HID * HID;
  u16*   bufA    = Rt2 + HID * HID;                   // NN*HID bf16
  u16*   bufB    = bufA + (size_t)NN * HID;           // NN*HID bf16

  hipMemsetAsync(d_ws, 0, (size_t)(8 * NG * HID) * sizeof(float), stream);

  // weight transpose + per-graph CSR build (LDS-histogram form; per call)
  wt_k<<<(FIN * HID + 3 * HID * HID) / 256, 256, 0, stream>>>(
      W1, W2, r1w1, r2w1, Wt1, Wt2, Rt1, Rt2);
  build_k<<<8 * 13, 1024, 0, stream>>>(src, dst, ew, cin, cout_, offs, csr);

  const int gemm_grid = 8 * 4 * 13;     // XCD-swizzled, 4 strips/graph
  const int gather_grid = 8 * 25 * 13;  // XCD-swizzled, 25 strips/graph

  // ---- layer 1 ----
  gemm1_k<<<gemm_grid, 256, 0, stream>>>(node_feats, Wt1, cout_, bufA);
  gather_k<<<gather_grid, 256, 0, stream>>>(bufA, csr, offs, cin, bufB, sx1, sq1);
  phi_pool_k<<<gemm_grid, 256, 0, stream>>>(bufB, sx1, sq1, g1a, g1g, g1b,
                                            Rt1, r1b1, ps1, hs1);
  finalize_k<<<NG, 64, 0, stream>>>(ps1, hs1, r1w2, r1b2, out, 0, 64);

  // ---- layer 2 ----
  gemm_norm_k<<<gemm_grid, 256, 0, stream>>>(bufB, Wt2, sx1, sq1, g1a, g1g, g1b,
                                             cout_, bufA);
  gather_k<<<gather_grid, 256, 0, stream>>>(bufA, csr, offs, cin, bufB, sx2, sq2);
  phi_pool_k<<<gemm_grid, 256, 0, stream>>>(bufB, sx2, sq2, g2a, g2g, g2b,
                                            Rt2, r2b1, ps2, hs2);
  finalize_k<<<NG, 64, 0, stream>>>(ps2, hs2, r2w2, r2b2, out, 192, 256);
}